// Round 2
// baseline (128.690 us; speedup 1.0000x reference)
//
#include <hip/hip_runtime.h>

#define B_ 16
#define T_ 800
#define D_ 256
#define K_ 64

// ---------------- Kernel A: dist -> softmax over K -> write r transposed [b][k][t] ------
// grid = (B*T)/64 = 200 blocks, 512 threads (8 waves). lane = t within 64-row group,
// wave = k-octet (8 k per thread). mu rows read via wave-uniform pointer -> s_load.
__global__ __launch_bounds__(512) void kernelA(
    const float* __restrict__ x, const float* __restrict__ mu,
    const float* __restrict__ prec, float* __restrict__ rT)
{
    __shared__ float mms[64];
    __shared__ float p2s[64];
    __shared__ float redm[8][64];
    __shared__ float reds[8][64];

    const int tid  = threadIdx.x;
    const int lane = tid & 63;
    const int wq   = __builtin_amdgcn_readfirstlane(tid >> 6);   // 0..7, wave-uniform
    const int row  = blockIdx.x * 64 + lane;                     // flat (b,t), 0..12799
    const int b    = row / T_;
    const int t    = row - b * T_;
    const int k0   = wq * 8;

    // mm[k] = ||mu_k||^2 (8 threads per k), p2[k] = prec[k]^2
    {
        const int k = tid >> 3, j = tid & 7;
        const float4* mg = (const float4*)(mu + k * D_ + j * 32);
        float s = 0.f;
        #pragma unroll
        for (int i = 0; i < 8; ++i) { float4 v = mg[i]; s += v.x*v.x + v.y*v.y + v.z*v.z + v.w*v.w; }
        s += __shfl_xor(s, 1); s += __shfl_xor(s, 2); s += __shfl_xor(s, 4);
        if (j == 0) mms[k] = s;
        if (tid < 64) { float p = prec[tid]; p2s[tid] = p * p; }
    }

    float acc[8];
    #pragma unroll
    for (int i = 0; i < 8; ++i) acc[i] = 0.f;
    float xx = 0.f;

    const float4* xrow = (const float4*)(x + (size_t)row * D_);

    #pragma unroll 1
    for (int c = 0; c < 4; ++c) {
        float4 xr[16];
        #pragma unroll
        for (int i = 0; i < 16; ++i) xr[i] = xrow[c * 16 + i];
        #pragma unroll
        for (int i = 0; i < 16; ++i) {
            float4 v = xr[i];
            xx = fmaf(v.x, v.x, xx); xx = fmaf(v.y, v.y, xx);
            xx = fmaf(v.z, v.z, xx); xx = fmaf(v.w, v.w, xx);
        }
        #pragma unroll
        for (int kk = 0; kk < 8; ++kk) {
            // wave-uniform pointer -> scalar loads
            const float4* mrow = (const float4*)(mu + (size_t)(k0 + kk) * D_ + c * 64);
            #pragma unroll
            for (int i = 0; i < 16; ++i) {
                float4 m = mrow[i];
                float4 v = xr[i];
                acc[kk] = fmaf(v.x, m.x, acc[kk]);
                acc[kk] = fmaf(v.y, m.y, acc[kk]);
                acc[kk] = fmaf(v.z, m.z, acc[kk]);
                acc[kk] = fmaf(v.w, m.w, acc[kk]);
            }
        }
    }
    __syncthreads();   // mms/p2s ready (overlapped with main compute is fine; barrier here)

    // llk_k = -p^2 * dist = p^2 * (2*dot - xx - mm)
    float llk[8];
    #pragma unroll
    for (int kk = 0; kk < 8; ++kk)
        llk[kk] = p2s[k0 + kk] * (2.f * acc[kk] - xx - mms[k0 + kk]);

    float pm = llk[0];
    #pragma unroll
    for (int kk = 1; kk < 8; ++kk) pm = fmaxf(pm, llk[kk]);
    redm[wq][lane] = pm;
    __syncthreads();
    float gm = redm[0][lane];
    #pragma unroll
    for (int j = 1; j < 8; ++j) gm = fmaxf(gm, redm[j][lane]);

    float e[8];
    float ps = 0.f;
    #pragma unroll
    for (int kk = 0; kk < 8; ++kk) { e[kk] = __expf(llk[kk] - gm); ps += e[kk]; }
    reds[wq][lane] = ps;
    __syncthreads();
    float gs = 0.f;
    #pragma unroll
    for (int j = 0; j < 8; ++j) gs += reds[j][lane];
    const float inv = 1.f / gs;

    // store transposed: rT[(b*64 + k)*800 + t], lanes = consecutive t -> coalesced
    float* rbase = rT + (size_t)b * K_ * T_ + t;
    #pragma unroll
    for (int kk = 0; kk < 8; ++kk)
        rbase[(size_t)(k0 + kk) * T_] = e[kk] * inv;
}

// ---------------- Kernel B: P[b,k,d] += sum_t rT[b,k,t] * x[b,t,d] (t-split 5) ----------
// grid = B * 4(dtiles of 64) * 5(tchunks of 160) = 320 blocks, 256 threads
// thread = (kk4 0..15, dq 0..15): owns k = kk4*4..+4, d = d0 + dq*4
__global__ __launch_bounds__(256) void kernelB(
    const float* __restrict__ x, const float* __restrict__ rT, float* __restrict__ P)
{
    __shared__ float xs[32 * 64];     // [tt][d] 8KB
    __shared__ float rs[64 * 33];     // [k][tt] padded 33 -> conflict-free

    const int tid = threadIdx.x;
    const int bid = blockIdx.x;
    const int b   = bid / 20;
    const int rem = bid % 20;
    const int d0  = (rem / 5) * 64;
    const int tc  = rem % 5;

    const int kk4 = tid >> 4;
    const int dq  = tid & 15;

    float4 acc[4];
    #pragma unroll
    for (int j = 0; j < 4; ++j) acc[j] = make_float4(0.f, 0.f, 0.f, 0.f);

    for (int s = 0; s < 5; ++s) {
        const int t0 = tc * 160 + s * 32;
        #pragma unroll
        for (int j = 0; j < 2; ++j) {
            int idx = tid + j * 256;                 // 0..511 float4
            int tt = idx >> 4, d4 = idx & 15;
            ((float4*)xs)[idx] =
                ((const float4*)x)[(size_t)(b * T_ + t0 + tt) * (D_ / 4) + (d0 >> 2) + d4];
        }
        #pragma unroll
        for (int j = 0; j < 8; ++j) {
            int idx = tid + j * 256;                 // 0..2047
            int k = idx >> 5, tt = idx & 31;
            rs[k * 33 + tt] = rT[(size_t)(b * K_ + k) * T_ + t0 + tt];
        }
        __syncthreads();
        #pragma unroll 4
        for (int tt = 0; tt < 32; ++tt) {
            float4 xv = ((const float4*)xs)[tt * 16 + dq];
            #pragma unroll
            for (int j = 0; j < 4; ++j) {
                float rv = rs[(kk4 * 4 + j) * 33 + tt];
                acc[j].x = fmaf(rv, xv.x, acc[j].x);
                acc[j].y = fmaf(rv, xv.y, acc[j].y);
                acc[j].z = fmaf(rv, xv.z, acc[j].z);
                acc[j].w = fmaf(rv, xv.w, acc[j].w);
            }
        }
        __syncthreads();
    }

    #pragma unroll
    for (int j = 0; j < 4; ++j) {
        float* Pp = P + (size_t)(b * K_ + kk4 * 4 + j) * D_ + d0 + dq * 4;
        atomicAdd(Pp + 0, acc[j].x);
        atomicAdd(Pp + 1, acc[j].y);
        atomicAdd(Pp + 2, acc[j].z);
        atomicAdd(Pp + 3, acc[j].w);
    }
}

// ---------------- Kernel C: S[b,k] = sum_t rT; out = P*inv - (S*inv)*mu ----------------
// grid = B*K = 1024 blocks, 64 threads (1 wave); lane = d-float4
__global__ __launch_bounds__(64) void kernelC(
    const float* __restrict__ rT, const float* __restrict__ P,
    const float* __restrict__ mu, float* __restrict__ out)
{
    const int bk   = blockIdx.x;        // b*64 + k
    const int lane = threadIdx.x;
    const int k    = bk & 63;

    const float* rrow = rT + (size_t)bk * T_;
    float s = 0.f;
    for (int i = lane; i < T_; i += 64) s += rrow[i];
    #pragma unroll
    for (int off = 32; off > 0; off >>= 1) s += __shfl_xor(s, off);

    const float inv = 1.f / (s + 1e-9f);
    const float sm  = s * inv;

    float4 p = ((const float4*)P)[bk * 64 + lane];
    float4 m = ((const float4*)mu)[k * 64 + lane];
    float4 o;
    o.x = p.x * inv - sm * m.x;
    o.y = p.y * inv - sm * m.y;
    o.z = p.z * inv - sm * m.z;
    o.w = p.w * inv - sm * m.w;
    ((float4*)out)[bk * 64 + lane] = o;
}

extern "C" void kernel_launch(void* const* d_in, const int* in_sizes, int n_in,
                              void* d_out, int out_size, void* d_ws, size_t ws_size,
                              hipStream_t stream) {
    const float* x    = (const float*)d_in[0];
    const float* mu   = (const float*)d_in[1];
    const float* prec = (const float*)d_in[2];
    float* out = (float*)d_out;

    float* rT = (float*)d_ws;                         // B*K*T = 819200 floats (transposed r)
    float* P  = rT + (size_t)B_ * K_ * T_;            // B*K*D = 262144 floats

    hipMemsetAsync(P, 0, (size_t)B_ * K_ * D_ * sizeof(float), stream);

    kernelA<<<(B_ * T_) / 64, 512, 0, stream>>>(x, mu, prec, rT);
    kernelB<<<B_ * 4 * 5, 256, 0, stream>>>(x, rT, P);
    kernelC<<<B_ * K_, 64, 0, stream>>>(rT, P, mu, out);
}